// Round 10
// baseline (197.050 us; speedup 1.0000x reference)
//
#include <hip/hip_runtime.h>
#include <hip/hip_bf16.h>

typedef unsigned short u16;
typedef __attribute__((ext_vector_type(8))) short short8;
typedef __attribute__((ext_vector_type(4))) float f32x4;
typedef __attribute__((ext_vector_type(4))) unsigned uint32x4;

__device__ __forceinline__ u16 f2b(float f) {
  unsigned u = __builtin_bit_cast(unsigned, f);
  unsigned r = u + 0x7fffu + ((u >> 16) & 1u);   // RNE bf16 (finite inputs)
  return (u16)(r >> 16);
}

__device__ __forceinline__ unsigned pkbf16(float lo, float hi) {
  unsigned r;
  asm("v_cvt_pk_bf16_f32 %0, %1, %2" : "=v"(r) : "v"(lo), "v"(hi));
  return r;
}

#define GLD_LDS16(gp, lp) __builtin_amdgcn_global_load_lds( \
    (const __attribute__((address_space(1))) void*)(gp),    \
    (__attribute__((address_space(3))) void*)(lp), 16, 0, 0)

// ---------------- fp32 -> bf16 convert ----------------
// Q-rows of w_qkv pre-scaled by scale*log2e; w_proj K-columns permuted
// i = a*256 + h*32 + c  ->  i' = h*96 + a*32 + c  (matches attn's feat layout).
__global__ __launch_bounds__(256) void cvt3(
    const float* __restrict__ x, const float* __restrict__ wq, const float* __restrict__ wp,
    u16* __restrict__ xb, u16* __restrict__ wqb, u16* __restrict__ wpb)
{
  const int NX = 8192 * 768 / 4, NQ = 2304 * 768 / 4, NP = 768 * 768 / 4;
  int i = blockIdx.x * 256 + threadIdx.x;
  if (i < NX) {
    float4 v = *(const float4*)&x[(size_t)i * 4];
    uint2 pk; pk.x = pkbf16(v.x, v.y); pk.y = pkbf16(v.z, v.w);
    *(uint2*)&xb[(size_t)i * 4] = pk;
  } else if (i < NX + NQ) {
    int j = i - NX;
    float sc = (j < 147456) ? 0.14724447f : 1.0f;   // rows 0..767 (Q) * scale*log2e
    float4 v = *(const float4*)&wq[(size_t)j * 4];
    uint2 pk; pk.x = pkbf16(v.x * sc, v.y * sc); pk.y = pkbf16(v.z * sc, v.w * sc);
    *(uint2*)&wqb[(size_t)j * 4] = pk;
  } else if (i < NX + NQ + NP) {
    int j = i - NX - NQ;
    int oo = (j * 4) / 768, ii = (j * 4) % 768;
    int a = ii >> 8, h = (ii >> 5) & 7, c = ii & 31;
    float4 v = *(const float4*)&wp[(size_t)j * 4];
    uint2 pk; pk.x = pkbf16(v.x, v.y); pk.y = pkbf16(v.z, v.w);
    *(uint2*)&wpb[oo * 768 + h * 96 + a * 32 + c] = pk;
  }
}

// ---------------- 128x128 bf16 GEMM, C = A @ Bt^T (both K-contiguous) ----------------
// vt_out != nullptr: block-columns with n0 >= 1536 (the V third of qkv) write to
// vt[bh][d][n] with the key-permutation (key o=16np+4gp+r -> slot 8gp+4np+r within
// each 32-token chunk) instead of writing Cb. Q/K block-columns write Cb normally.
__global__ __launch_bounds__(256) void gemm_bt(
    const u16* __restrict__ A, const u16* __restrict__ Bt,
    u16* __restrict__ Cb, u16* __restrict__ vt_out, int M, int N, int K)
{
  __shared__ u16 Al[128 * 32];
  __shared__ u16 Bl[128 * 32];
  const int tid = threadIdx.x;
  const int lane = tid & 63, wave = tid >> 6;
  const int wr = wave >> 1, wc = wave & 1;
  const int g = lane >> 4, c16 = lane & 15;
  const int m0 = blockIdx.y * 128, n0 = blockIdx.x * 128;

  f32x4 acc[4][4] = {};

  const int c0 = tid, c1 = tid + 256;
  const int r0 = c0 >> 2, o0 = (c0 & 3) * 8;
  const int r1 = c1 >> 2, o1 = (c1 & 3) * 8;
  const u16* a0 = A + (size_t)(m0 + r0) * K + o0;
  const u16* a1 = A + (size_t)(m0 + r1) * K + o1;
  const u16* b0 = Bt + (size_t)(n0 + r0) * K + o0;
  const u16* b1 = Bt + (size_t)(n0 + r1) * K + o1;

  for (int k0 = 0; k0 < K; k0 += 32) {
    GLD_LDS16(a0 + k0, Al + c0 * 8);
    GLD_LDS16(a1 + k0, Al + c1 * 8);
    GLD_LDS16(b0 + k0, Bl + c0 * 8);
    GLD_LDS16(b1 + k0, Bl + c1 * 8);
    __syncthreads();
    short8 af[4], bfr[4];
#pragma unroll
    for (int m = 0; m < 4; ++m)
      af[m] = *(const short8*)&Al[(wr * 64 + m * 16 + c16) * 32 + g * 8];
#pragma unroll
    for (int n = 0; n < 4; ++n)
      bfr[n] = *(const short8*)&Bl[(wc * 64 + n * 16 + c16) * 32 + g * 8];
#pragma unroll
    for (int m = 0; m < 4; ++m)
#pragma unroll
      for (int n = 0; n < 4; ++n)
        acc[m][n] = __builtin_amdgcn_mfma_f32_16x16x32_bf16(af[m], bfr[n], acc[m][n], 0, 0, 0);
    __syncthreads();
  }

  if (vt_out && n0 >= 1536) {
    // V region -> vt[bh][d][token-slot] (key-permuted), 8B stores
#pragma unroll
    for (int m = 0; m < 4; ++m) {
      const int row0 = m0 + wr * 64 + m * 16 + g * 4;   // 4-aligned token run
      const int bb = row0 >> 10, nb = row0 & 1023;
      const int chunk = nb & ~31, o = nb & 31;
      const int slot0 = ((o >> 2) & 3) * 8 + ((o >> 4) & 1) * 4;  // r=0
#pragma unroll
      for (int n = 0; n < 4; ++n) {
        const int colg = n0 - 1536 + wc * 64 + n * 16 + c16;   // 0..767
        const int hh = colg / 96, dd = colg % 96;
        uint2 pk;
        pk.x = pkbf16(acc[m][n][0], acc[m][n][1]);
        pk.y = pkbf16(acc[m][n][2], acc[m][n][3]);
        *(uint2*)&vt_out[((size_t)(bb * 8 + hh) * 96 + dd) * 1024 + chunk + slot0] = pk;
      }
    }
  } else {
#pragma unroll
    for (int m = 0; m < 4; ++m) {
      const int row = m0 + wr * 64 + m * 16 + g * 4;
#pragma unroll
      for (int n = 0; n < 4; ++n) {
        const int col = n0 + wc * 64 + n * 16 + c16;
#pragma unroll
        for (int j = 0; j < 4; ++j)
          Cb[(size_t)(row + j) * N + col] = f2b(acc[m][n][j]);
      }
    }
  }
}

// ---------------- 128x64 bf16 GEMM for the proj (fp32 out + bias) ----------------
// N=768 -> 12x64 = 768 blocks (3/CU) vs 384 at 128-wide tiles (occupancy-starved).
__global__ __launch_bounds__(256) void gemm_bt64(
    const u16* __restrict__ A, const u16* __restrict__ Bt,
    float* __restrict__ Cf, const float* __restrict__ bias, int M, int N, int K)
{
  __shared__ u16 Al[128 * 32];
  __shared__ u16 Bl[64 * 32];
  const int tid = threadIdx.x;
  const int lane = tid & 63, wave = tid >> 6;
  const int g = lane >> 4, c16 = lane & 15;
  const int m0 = blockIdx.y * 128, n0 = blockIdx.x * 64;

  f32x4 acc[2][4] = {};

  const int c0 = tid, c1 = tid + 256;
  const int rA0 = c0 >> 2, oA0 = (c0 & 3) * 8;
  const int rA1 = c1 >> 2, oA1 = (c1 & 3) * 8;
  const u16* a0 = A + (size_t)(m0 + rA0) * K + oA0;
  const u16* a1 = A + (size_t)(m0 + rA1) * K + oA1;
  const u16* b0 = Bt + (size_t)(n0 + rA0) * K + oA0;   // rA0 in 0..63 for tid<256? tid>>2 up to 63 ✓

  for (int k0 = 0; k0 < K; k0 += 32) {
    GLD_LDS16(a0 + k0, Al + c0 * 8);
    GLD_LDS16(a1 + k0, Al + c1 * 8);
    if (tid < 256) GLD_LDS16(b0 + k0, Bl + c0 * 8);   // 64*4 = 256 chunks
    __syncthreads();
    short8 af[2], bfr[4];
#pragma unroll
    for (int m = 0; m < 2; ++m)
      af[m] = *(const short8*)&Al[(wave * 32 + m * 16 + c16) * 32 + g * 8];
#pragma unroll
    for (int n = 0; n < 4; ++n)
      bfr[n] = *(const short8*)&Bl[(n * 16 + c16) * 32 + g * 8];
#pragma unroll
    for (int m = 0; m < 2; ++m)
#pragma unroll
      for (int n = 0; n < 4; ++n)
        acc[m][n] = __builtin_amdgcn_mfma_f32_16x16x32_bf16(af[m], bfr[n], acc[m][n], 0, 0, 0);
    __syncthreads();
  }

#pragma unroll
  for (int m = 0; m < 2; ++m) {
    const int row = m0 + wave * 32 + m * 16 + g * 4;
#pragma unroll
    for (int n = 0; n < 4; ++n) {
      const int col = n0 + n * 16 + c16;
      const float bb = bias[col];
#pragma unroll
      for (int j = 0; j < 4; ++j)
        Cf[(size_t)(row + j) * N + col] = acc[m][n][j] + bb;
    }
  }
}

// ---------------- tri-attention, 3-way att-split, double-buffered LDS ----------------
// grid 1536: id = h + 8*(aidx + 3*(qt + 8*b)); id&7 = h keeps all blocks sharing
// one (b,h)'s K/V on one XCD. Block aidx computes ONE output (x3/x4/x5) for 128 q.
// ONE barrier per tile: {write buf[t&1]; prefetch t+1; barrier; compute buf[t&1]}
// (write(t) vs reads(t-2) separated by barrier(t-1)). K/V tiles UNPADDED with
// slot-XOR swizzle (slot ^= row&3 / row&7 on both write and read) -> b128 floor,
// 16KB/stage. LDS = 2 bufs + dedicated Ol = 40960 B = exactly 4 blocks/CU.
// amdgpu_waves_per_eu(2,4): caps occupancy target -> 128-VGPR budget, no spill
// (R9 confirmed: WRITE collapsed 115->12.4 MB).
__global__ __attribute__((amdgpu_flat_work_group_size(256, 256)))
__attribute__((amdgpu_waves_per_eu(2, 4)))
void attn_kernel(
    const u16* __restrict__ qkv, const u16* __restrict__ vt, u16* __restrict__ feat)
{
  __shared__ u16 smem[20480];   // 2 x (K 4096 + V 4096) | Ol 4096  = 40960 B

  const int tid = threadIdx.x;
  const int lane = tid & 63, wave = tid >> 6;
  const int g = lane >> 4, c16 = lane & 15;
  const int id = blockIdx.x;
  const int h = id & 7;
  const int r3 = id >> 3;
  const int aidx = r3 % 3;
  const int t2 = r3 / 3;
  const int qt = t2 & 7, b = t2 >> 3;
  const int bh = b * 8 + h;
  const int q0 = qt * 128 + wave * 32;
  const size_t tb = (size_t)b * 1024;

  const int p0 = (aidx == 2) ? 1 : 0;        // K/V parts per att
  const int p1 = (aidx == 0) ? 1 : 2;
  const int qoff = (aidx == 0) ? 32 : 64;    // q4 : q5

  short8 qf[2];
#pragma unroll
  for (int m = 0; m < 2; ++m)
    qf[m] = *(const short8*)&qkv[(tb + q0 + m * 16 + c16) * 2304 + h * 96 + qoff + 8 * g];

  short8 ones;
#pragma unroll
  for (int i = 0; i < 8; ++i) ones[i] = (short)0x3F80;  // bf16 1.0

  f32x4 acc[2][2] = {};   // [m][n]
  f32x4 lsv[2] = {};      // row-sums, same layout

  // staging: K per part: 64 keys x 32d, lane (kkey=tid>>2, kcc=tid&3)
  //          V per part: 32 d-rows x 64 keys, lane (vd=tid>>3, vc=tid&7)
  const int kkey = tid >> 2, kcc = tid & 3;
  const int vd = tid >> 3, vc = tid & 7;
  const int P[2] = { p0, p1 };
  uint4 kst[2], vst[2];
#pragma unroll
  for (int i = 0; i < 2; ++i) {
    kst[i] = *(const uint4*)&qkv[(tb + kkey) * 2304 + 768 + h * 96 + P[i] * 32 + kcc * 8];
    vst[i] = *(const uint4*)&vt[((size_t)bh * 96 + P[i] * 32 + vd) * 1024 + vc * 8];
  }
  // swizzled write offsets (u16 units), fixed per lane
  const int kwr = kkey * 32 + (kcc ^ (kkey & 3)) * 8;
  const int vwr = vd * 64 + (vc ^ (vd & 7)) * 8;

  for (int t = 0; t < 16; ++t) {
    u16* Kb = smem + (t & 1) * 8192;
    u16* Vb = Kb + 4096;
#pragma unroll
    for (int i = 0; i < 2; ++i) {
      *(uint4*)&Kb[i * 2048 + kwr] = kst[i];
      *(uint4*)&Vb[i * 2048 + vwr] = vst[i];
    }
    if (t < 15) {  // prefetch next tile into regs; latency hides under compute
      int kv0 = (t + 1) * 64;
#pragma unroll
      for (int i = 0; i < 2; ++i) {
        kst[i] = *(const uint4*)&qkv[(tb + kv0 + kkey) * 2304 + 768 + h * 96 + P[i] * 32 + kcc * 8];
        vst[i] = *(const uint4*)&vt[((size_t)bh * 96 + P[i] * 32 + vd) * 1024 + kv0 + vc * 8];
      }
    }
    __syncthreads();

#pragma unroll
    for (int u = 0; u < 2; ++u) {
      short8 kf[4], vf[2][2];
#pragma unroll
      for (int n = 0; n < 4; ++n) {
        const int row = n * 16 + c16;
        kf[n] = *(const short8*)&Kb[u * 2048 + row * 32 + ((g ^ (c16 & 3)) * 8)];
      }
#pragma unroll
      for (int n = 0; n < 2; ++n)
#pragma unroll
        for (int kk = 0; kk < 2; ++kk) {
          const int row = n * 16 + c16;   // d within part
          vf[n][kk] = *(const short8*)&Vb[u * 2048 + row * 64 + (((kk * 4 + g) ^ (c16 & 7)) * 8)];
        }

      const f32x4 z = {0.f, 0.f, 0.f, 0.f};
#pragma unroll
      for (int m = 0; m < 2; ++m) {
        f32x4 St[4];
        __builtin_amdgcn_s_setprio(1);
#pragma unroll
        for (int n = 0; n < 4; ++n)
          St[n] = __builtin_amdgcn_mfma_f32_16x16x32_bf16(kf[n], qf[m], z, 0, 0, 0);
        __builtin_amdgcn_s_setprio(0);
        short8 pa[2];
#pragma unroll
        for (int kk = 0; kk < 2; ++kk) {
          uint32x4 w;
          w.x = pkbf16(__builtin_amdgcn_exp2f(St[2 * kk][0]),     __builtin_amdgcn_exp2f(St[2 * kk][1]));
          w.y = pkbf16(__builtin_amdgcn_exp2f(St[2 * kk][2]),     __builtin_amdgcn_exp2f(St[2 * kk][3]));
          w.z = pkbf16(__builtin_amdgcn_exp2f(St[2 * kk + 1][0]), __builtin_amdgcn_exp2f(St[2 * kk + 1][1]));
          w.w = pkbf16(__builtin_amdgcn_exp2f(St[2 * kk + 1][2]), __builtin_amdgcn_exp2f(St[2 * kk + 1][3]));
          pa[kk] = __builtin_bit_cast(short8, w);
        }
        __builtin_amdgcn_s_setprio(1);
#pragma unroll
        for (int n = 0; n < 2; ++n)
#pragma unroll
          for (int kk = 0; kk < 2; ++kk)
            acc[m][n] = __builtin_amdgcn_mfma_f32_16x16x32_bf16(pa[kk], vf[n][kk], acc[m][n], 0, 0, 0);
#pragma unroll
        for (int kk = 0; kk < 2; ++kk)
          lsv[m] = __builtin_amdgcn_mfma_f32_16x16x32_bf16(pa[kk], ones, lsv[m], 0, 0, 0);
        __builtin_amdgcn_s_setprio(0);
      }
    }
  }

  // epilogue: dedicated per-wave Ol region -> no barrier (wave-local lgkmcnt order)
  u16* Ol = smem + 16384 + wave * 1024;   // [32 rows][32 cols]
#pragma unroll
  for (int m = 0; m < 2; ++m) {
    f32x4 inv;
#pragma unroll
    for (int r = 0; r < 4; ++r) inv[r] = 1.0f / lsv[m][r];
#pragma unroll
    for (int n = 0; n < 2; ++n)
#pragma unroll
      for (int r = 0; r < 4; ++r)
        Ol[(m * 16 + g * 4 + r) * 32 + n * 16 + c16] = f2b(acc[m][n][r] * inv[r]);
  }
#pragma unroll
  for (int i = 0; i < 2; ++i) {
    int idx = lane + 64 * i;           // 0..127
    int row = idx >> 2, q4 = idx & 3;
    uint4 val = *(const uint4*)&Ol[row * 32 + q4 * 8];
    *(uint4*)&feat[(tb + q0 + row) * 768 + h * 96 + aidx * 32 + q4 * 8] = val;
  }
}

// ---------------- launch ----------------
extern "C" void kernel_launch(void* const* d_in, const int* in_sizes, int n_in,
                              void* d_out, int out_size, void* d_ws, size_t ws_size,
                              hipStream_t stream) {
  const float* x  = (const float*)d_in[0];
  const float* wq = (const float*)d_in[1];
  const float* wp = (const float*)d_in[2];
  const float* bp = (const float*)d_in[3];
  float* out = (float*)d_out;

  char* ws = (char*)d_ws;
  u16* xb    = (u16*)(ws);                // 12,582,912 B  (reused as feat after GEMM1)
  u16* wqb   = (u16*)(ws + 12582912);     //  3,538,944 B
  u16* wpb   = (u16*)(ws + 16121856);     //  1,179,648 B
  u16* qkvb  = (u16*)(ws + 17301504);     // 37,748,736 B (V third unused)
  u16* vtb   = (u16*)(ws + 55050240);     // 12,582,912 B  (end: 67,633,152)
  u16* featb = xb;                        // xb is dead after GEMM1

  cvt3<<<8448, 256, 0, stream>>>(x, wq, wp, xb, wqb, wpb);
  gemm_bt<<<dim3(18, 64), 256, 0, stream>>>(xb, wqb, qkvb, vtb, 8192, 2304, 768);
  attn_kernel<<<1536, 256, 0, stream>>>(qkvb, vtb, featb);
  gemm_bt64<<<dim3(12, 64), 256, 0, stream>>>(featb, wpb, out, bp, 8192, 768, 768);
}

// Round 11
// 169.722 us; speedup vs baseline: 1.1610x; 1.1610x over previous
//
#include <hip/hip_runtime.h>
#include <hip/hip_bf16.h>

typedef unsigned short u16;
typedef __attribute__((ext_vector_type(8))) short short8;
typedef __attribute__((ext_vector_type(4))) float f32x4;
typedef __attribute__((ext_vector_type(4))) unsigned uint32x4;

__device__ __forceinline__ u16 f2b(float f) {
  unsigned u = __builtin_bit_cast(unsigned, f);
  unsigned r = u + 0x7fffu + ((u >> 16) & 1u);   // RNE bf16 (finite inputs)
  return (u16)(r >> 16);
}

__device__ __forceinline__ unsigned pkbf16(float lo, float hi) {
  unsigned r;
  asm("v_cvt_pk_bf16_f32 %0, %1, %2" : "=v"(r) : "v"(lo), "v"(hi));
  return r;
}

#define GLD_LDS16(gp, lp) __builtin_amdgcn_global_load_lds( \
    (const __attribute__((address_space(1))) void*)(gp),    \
    (__attribute__((address_space(3))) void*)(lp), 16, 0, 0)

// ---------------- fp32 -> bf16 convert ----------------
// Q-rows of w_qkv pre-scaled by scale*log2e; w_proj K-columns permuted
// i = a*256 + h*32 + c  ->  i' = h*96 + a*32 + c  (matches attn's feat layout).
__global__ __launch_bounds__(256) void cvt3(
    const float* __restrict__ x, const float* __restrict__ wq, const float* __restrict__ wp,
    u16* __restrict__ xb, u16* __restrict__ wqb, u16* __restrict__ wpb)
{
  const int NX = 8192 * 768 / 4, NQ = 2304 * 768 / 4, NP = 768 * 768 / 4;
  int i = blockIdx.x * 256 + threadIdx.x;
  if (i < NX) {
    float4 v = *(const float4*)&x[(size_t)i * 4];
    uint2 pk; pk.x = pkbf16(v.x, v.y); pk.y = pkbf16(v.z, v.w);
    *(uint2*)&xb[(size_t)i * 4] = pk;
  } else if (i < NX + NQ) {
    int j = i - NX;
    float sc = (j < 147456) ? 0.14724447f : 1.0f;   // rows 0..767 (Q) * scale*log2e
    float4 v = *(const float4*)&wq[(size_t)j * 4];
    uint2 pk; pk.x = pkbf16(v.x * sc, v.y * sc); pk.y = pkbf16(v.z * sc, v.w * sc);
    *(uint2*)&wqb[(size_t)j * 4] = pk;
  } else if (i < NX + NQ + NP) {
    int j = i - NX - NQ;
    int oo = (j * 4) / 768, ii = (j * 4) % 768;
    int a = ii >> 8, h = (ii >> 5) & 7, c = ii & 31;
    float4 v = *(const float4*)&wp[(size_t)j * 4];
    uint2 pk; pk.x = pkbf16(v.x, v.y); pk.y = pkbf16(v.z, v.w);
    *(uint2*)&wpb[oo * 768 + h * 96 + a * 32 + c] = pk;
  }
}

// ---------------- 128x128 bf16 GEMM, C = A @ Bt^T (both K-contiguous) ----------------
// vt_out != nullptr: block-columns with n0 >= 1536 (the V third of qkv) write to
// vt[bh][d][n] with the key-permutation (key o=16np+4gp+r -> slot 8gp+4np+r within
// each 32-token chunk) instead of writing Cb. Q/K block-columns write Cb normally.
__global__ __launch_bounds__(256) void gemm_bt(
    const u16* __restrict__ A, const u16* __restrict__ Bt,
    u16* __restrict__ Cb, u16* __restrict__ vt_out, int M, int N, int K)
{
  __shared__ u16 Al[128 * 32];
  __shared__ u16 Bl[128 * 32];
  const int tid = threadIdx.x;
  const int lane = tid & 63, wave = tid >> 6;
  const int wr = wave >> 1, wc = wave & 1;
  const int g = lane >> 4, c16 = lane & 15;
  const int m0 = blockIdx.y * 128, n0 = blockIdx.x * 128;

  f32x4 acc[4][4] = {};

  const int c0 = tid, c1 = tid + 256;
  const int r0 = c0 >> 2, o0 = (c0 & 3) * 8;
  const int r1 = c1 >> 2, o1 = (c1 & 3) * 8;
  const u16* a0 = A + (size_t)(m0 + r0) * K + o0;
  const u16* a1 = A + (size_t)(m0 + r1) * K + o1;
  const u16* b0 = Bt + (size_t)(n0 + r0) * K + o0;
  const u16* b1 = Bt + (size_t)(n0 + r1) * K + o1;

  for (int k0 = 0; k0 < K; k0 += 32) {
    GLD_LDS16(a0 + k0, Al + c0 * 8);
    GLD_LDS16(a1 + k0, Al + c1 * 8);
    GLD_LDS16(b0 + k0, Bl + c0 * 8);
    GLD_LDS16(b1 + k0, Bl + c1 * 8);
    __syncthreads();
    short8 af[4], bfr[4];
#pragma unroll
    for (int m = 0; m < 4; ++m)
      af[m] = *(const short8*)&Al[(wr * 64 + m * 16 + c16) * 32 + g * 8];
#pragma unroll
    for (int n = 0; n < 4; ++n)
      bfr[n] = *(const short8*)&Bl[(wc * 64 + n * 16 + c16) * 32 + g * 8];
#pragma unroll
    for (int m = 0; m < 4; ++m)
#pragma unroll
      for (int n = 0; n < 4; ++n)
        acc[m][n] = __builtin_amdgcn_mfma_f32_16x16x32_bf16(af[m], bfr[n], acc[m][n], 0, 0, 0);
    __syncthreads();
  }

  if (vt_out && n0 >= 1536) {
    // V region -> vt[bh][d][token-slot] (key-permuted), 8B stores
#pragma unroll
    for (int m = 0; m < 4; ++m) {
      const int row0 = m0 + wr * 64 + m * 16 + g * 4;   // 4-aligned token run
      const int bb = row0 >> 10, nb = row0 & 1023;
      const int chunk = nb & ~31, o = nb & 31;
      const int slot0 = ((o >> 2) & 3) * 8 + ((o >> 4) & 1) * 4;  // r=0
#pragma unroll
      for (int n = 0; n < 4; ++n) {
        const int colg = n0 - 1536 + wc * 64 + n * 16 + c16;   // 0..767
        const int hh = colg / 96, dd = colg % 96;
        uint2 pk;
        pk.x = pkbf16(acc[m][n][0], acc[m][n][1]);
        pk.y = pkbf16(acc[m][n][2], acc[m][n][3]);
        *(uint2*)&vt_out[((size_t)(bb * 8 + hh) * 96 + dd) * 1024 + chunk + slot0] = pk;
      }
    }
  } else {
#pragma unroll
    for (int m = 0; m < 4; ++m) {
      const int row = m0 + wr * 64 + m * 16 + g * 4;
#pragma unroll
      for (int n = 0; n < 4; ++n) {
        const int col = n0 + wc * 64 + n * 16 + c16;
#pragma unroll
        for (int j = 0; j < 4; ++j)
          Cb[(size_t)(row + j) * N + col] = f2b(acc[m][n][j]);
      }
    }
  }
}

// ---------------- 128x64 bf16 GEMM for the proj (fp32 out + bias) ----------------
// N=768 -> 12x64 = 768 blocks (3/CU) vs 384 at 128-wide tiles (occupancy-starved).
__global__ __launch_bounds__(256) void gemm_bt64(
    const u16* __restrict__ A, const u16* __restrict__ Bt,
    float* __restrict__ Cf, const float* __restrict__ bias, int M, int N, int K)
{
  __shared__ u16 Al[128 * 32];
  __shared__ u16 Bl[64 * 32];
  const int tid = threadIdx.x;
  const int lane = tid & 63, wave = tid >> 6;
  const int g = lane >> 4, c16 = lane & 15;
  const int m0 = blockIdx.y * 128, n0 = blockIdx.x * 64;

  f32x4 acc[2][4] = {};

  const int c0 = tid, c1 = tid + 256;
  const int rA0 = c0 >> 2, oA0 = (c0 & 3) * 8;
  const int rA1 = c1 >> 2, oA1 = (c1 & 3) * 8;
  const u16* a0 = A + (size_t)(m0 + rA0) * K + oA0;
  const u16* a1 = A + (size_t)(m0 + rA1) * K + oA1;
  const u16* b0 = Bt + (size_t)(n0 + rA0) * K + oA0;

  for (int k0 = 0; k0 < K; k0 += 32) {
    GLD_LDS16(a0 + k0, Al + c0 * 8);
    GLD_LDS16(a1 + k0, Al + c1 * 8);
    if (tid < 256) GLD_LDS16(b0 + k0, Bl + c0 * 8);   // 64*4 = 256 chunks
    __syncthreads();
    short8 af[2], bfr[4];
#pragma unroll
    for (int m = 0; m < 2; ++m)
      af[m] = *(const short8*)&Al[(wave * 32 + m * 16 + c16) * 32 + g * 8];
#pragma unroll
    for (int n = 0; n < 4; ++n)
      bfr[n] = *(const short8*)&Bl[(n * 16 + c16) * 32 + g * 8];
#pragma unroll
    for (int m = 0; m < 2; ++m)
#pragma unroll
      for (int n = 0; n < 4; ++n)
        acc[m][n] = __builtin_amdgcn_mfma_f32_16x16x32_bf16(af[m], bfr[n], acc[m][n], 0, 0, 0);
    __syncthreads();
  }

#pragma unroll
  for (int m = 0; m < 2; ++m) {
    const int row = m0 + wave * 32 + m * 16 + g * 4;
#pragma unroll
    for (int n = 0; n < 4; ++n) {
      const int col = n0 + n * 16 + c16;
      const float bb = bias[col];
#pragma unroll
      for (int j = 0; j < 4; ++j)
        Cf[(size_t)(row + j) * N + col] = acc[m][n][j] + bb;
    }
  }
}

// ---------------- tri-attention, 3-way att-split (R9-proven shape) ----------------
// grid 1536: id = h + 8*(aidx + 3*(qt + 8*b)); id&7 = h keeps all blocks sharing
// one (b,h)'s K/V on one XCD. Block aidx computes ONE output (x3/x4/x5) for 128 q:
// aidx0: q4 vs parts(k3,k4); aidx1: q5 vs (k3,k5); aidx2: q5 vs (k4,k5).
// amdgpu_waves_per_eu(2,4): caps occupancy target; compiler pads LDS to 35840
// (4 blocks/CU) and codegen stays spill-free (R9: WRITE 12.4 MB, 93.7 us).
// NOTE (R10 post-mortem): structural edits to this loop (double-buffer, XOR
// swizzle, 1-barrier) flip codegen back into scratch-spill mode (+104 MB WRITE,
// +35 us) at identical reported VGPR. This exact shape is the proven-good one;
// do not restructure the hot loop without checking WRITE_SIZE.
__global__ __attribute__((amdgpu_flat_work_group_size(256, 256)))
__attribute__((amdgpu_waves_per_eu(2, 4)))
void attn_kernel(
    const u16* __restrict__ qkv, const u16* __restrict__ vt, u16* __restrict__ feat)
{
  __shared__ u16 smem[2 * 2560 + 64 * 72];   // Kl 2x[64][40] | Vl [64][72] = 19456 B
  u16* Kl = smem;
  u16* Vl = smem + 2 * 2560;

  const int tid = threadIdx.x;
  const int lane = tid & 63, wave = tid >> 6;
  const int g = lane >> 4, c16 = lane & 15;
  const int id = blockIdx.x;
  const int h = id & 7;
  const int r3 = id >> 3;
  const int aidx = r3 % 3;
  const int t2 = r3 / 3;
  const int qt = t2 & 7, b = t2 >> 3;
  const int bh = b * 8 + h;
  const int q0 = qt * 128 + wave * 32;
  const size_t tb = (size_t)b * 1024;

  const int p0 = (aidx == 2) ? 1 : 0;        // K/V parts per att
  const int p1 = (aidx == 0) ? 1 : 2;
  const int qoff = (aidx == 0) ? 32 : 64;    // q4 : q5

  short8 qf[2];
#pragma unroll
  for (int m = 0; m < 2; ++m)
    qf[m] = *(const short8*)&qkv[(tb + q0 + m * 16 + c16) * 2304 + h * 96 + qoff + 8 * g];

  short8 ones;
#pragma unroll
  for (int i = 0; i < 8; ++i) ones[i] = (short)0x3F80;  // bf16 1.0

  f32x4 acc[2][2] = {};   // [m][n]
  f32x4 lsv[2] = {};      // row-sums, same layout

  // staging: K: per part, 64 keys x 32d = 256 uint4; key=tid>>2, cc=tid&3
  //          V: per part, 32 d-rows x 64 keys = 256 uint4; d=tid>>3, c=tid&7
  const int kkey = tid >> 2, kcc = tid & 3;
  const int vd = tid >> 3, vc = tid & 7;
  const int P[2] = { p0, p1 };
  uint4 kst[2], vst[2];
#pragma unroll
  for (int i = 0; i < 2; ++i) {
    kst[i] = *(const uint4*)&qkv[(tb + kkey) * 2304 + 768 + h * 96 + P[i] * 32 + kcc * 8];
    vst[i] = *(const uint4*)&vt[((size_t)bh * 96 + P[i] * 32 + vd) * 1024 + vc * 8];
  }

  for (int t = 0; t < 16; ++t) {
    __syncthreads();
#pragma unroll
    for (int i = 0; i < 2; ++i) {
      *(uint4*)&Kl[i * 2560 + kkey * 40 + kcc * 8] = kst[i];
      *(uint4*)&Vl[(i * 32 + vd) * 72 + vc * 8] = vst[i];
    }
    if (t < 15) {  // prefetch next tile into regs; latency hides under compute
      int kv0 = (t + 1) * 64;
#pragma unroll
      for (int i = 0; i < 2; ++i) {
        kst[i] = *(const uint4*)&qkv[(tb + kv0 + kkey) * 2304 + 768 + h * 96 + P[i] * 32 + kcc * 8];
        vst[i] = *(const uint4*)&vt[((size_t)bh * 96 + P[i] * 32 + vd) * 1024 + kv0 + vc * 8];
      }
    }
    __syncthreads();

#pragma unroll
    for (int u = 0; u < 2; ++u) {
      short8 kf[4], vf[2][2];
#pragma unroll
      for (int n = 0; n < 4; ++n)
        kf[n] = *(const short8*)&Kl[u * 2560 + (n * 16 + c16) * 40 + g * 8];
#pragma unroll
      for (int n = 0; n < 2; ++n)
#pragma unroll
        for (int kk = 0; kk < 2; ++kk)
          vf[n][kk] = *(const short8*)&Vl[(u * 32 + n * 16 + c16) * 72 + kk * 32 + g * 8];

      const f32x4 z = {0.f, 0.f, 0.f, 0.f};
#pragma unroll
      for (int m = 0; m < 2; ++m) {
        f32x4 St[4];
        __builtin_amdgcn_s_setprio(1);
#pragma unroll
        for (int n = 0; n < 4; ++n)
          St[n] = __builtin_amdgcn_mfma_f32_16x16x32_bf16(kf[n], qf[m], z, 0, 0, 0);
        __builtin_amdgcn_s_setprio(0);
        short8 pa[2];
#pragma unroll
        for (int kk = 0; kk < 2; ++kk) {
          uint32x4 w;
          w.x = pkbf16(__builtin_amdgcn_exp2f(St[2 * kk][0]),     __builtin_amdgcn_exp2f(St[2 * kk][1]));
          w.y = pkbf16(__builtin_amdgcn_exp2f(St[2 * kk][2]),     __builtin_amdgcn_exp2f(St[2 * kk][3]));
          w.z = pkbf16(__builtin_amdgcn_exp2f(St[2 * kk + 1][0]), __builtin_amdgcn_exp2f(St[2 * kk + 1][1]));
          w.w = pkbf16(__builtin_amdgcn_exp2f(St[2 * kk + 1][2]), __builtin_amdgcn_exp2f(St[2 * kk + 1][3]));
          pa[kk] = __builtin_bit_cast(short8, w);
        }
        __builtin_amdgcn_s_setprio(1);
#pragma unroll
        for (int n = 0; n < 2; ++n)
#pragma unroll
          for (int kk = 0; kk < 2; ++kk)
            acc[m][n] = __builtin_amdgcn_mfma_f32_16x16x32_bf16(pa[kk], vf[n][kk], acc[m][n], 0, 0, 0);
#pragma unroll
        for (int kk = 0; kk < 2; ++kk)
          lsv[m] = __builtin_amdgcn_mfma_f32_16x16x32_bf16(pa[kk], ones, lsv[m], 0, 0, 0);
        __builtin_amdgcn_s_setprio(0);
      }
    }
  }

  // epilogue: stage per-wave 32x32 tile in LDS (overlay Kl), coalesced 16B stores
  __syncthreads();   // all waves done reading Kl/Vl
  u16* Ol = smem + wave * 1024;   // [32 rows][32 cols]
#pragma unroll
  for (int m = 0; m < 2; ++m) {
    f32x4 inv;
#pragma unroll
    for (int r = 0; r < 4; ++r) inv[r] = 1.0f / lsv[m][r];
#pragma unroll
    for (int n = 0; n < 2; ++n)
#pragma unroll
      for (int r = 0; r < 4; ++r)
        Ol[(m * 16 + g * 4 + r) * 32 + n * 16 + c16] = f2b(acc[m][n][r] * inv[r]);
  }
  // per-wave private Ol slice: same-wave ds ordering via lgkmcnt, no barrier needed
#pragma unroll
  for (int i = 0; i < 2; ++i) {
    int idx = lane + 64 * i;           // 0..127
    int row = idx >> 2, q4 = idx & 3;
    uint4 val = *(const uint4*)&Ol[row * 32 + q4 * 8];
    *(uint4*)&feat[(tb + q0 + row) * 768 + h * 96 + aidx * 32 + q4 * 8] = val;
  }
}

// ---------------- launch ----------------
extern "C" void kernel_launch(void* const* d_in, const int* in_sizes, int n_in,
                              void* d_out, int out_size, void* d_ws, size_t ws_size,
                              hipStream_t stream) {
  const float* x  = (const float*)d_in[0];
  const float* wq = (const float*)d_in[1];
  const float* wp = (const float*)d_in[2];
  const float* bp = (const float*)d_in[3];
  float* out = (float*)d_out;

  char* ws = (char*)d_ws;
  u16* xb    = (u16*)(ws);                // 12,582,912 B  (reused as feat after GEMM1)
  u16* wqb   = (u16*)(ws + 12582912);     //  3,538,944 B
  u16* wpb   = (u16*)(ws + 16121856);     //  1,179,648 B
  u16* qkvb  = (u16*)(ws + 17301504);     // 37,748,736 B (V third unused)
  u16* vtb   = (u16*)(ws + 55050240);     // 12,582,912 B  (end: 67,633,152)
  u16* featb = xb;                        // xb is dead after GEMM1

  cvt3<<<8448, 256, 0, stream>>>(x, wq, wp, xb, wqb, wpb);
  gemm_bt<<<dim3(18, 64), 256, 0, stream>>>(xb, wqb, qkvb, vtb, 8192, 2304, 768);
  attn_kernel<<<1536, 256, 0, stream>>>(qkvb, vtb, featb);
  gemm_bt64<<<dim3(12, 64), 256, 0, stream>>>(featb, wpb, out, bp, 8192, 768, 768);
}